// Round 10
// baseline (104.376 us; speedup 1.0000x reference)
//
#include <hip/hip_runtime.h>

#define N_NODES 10000
#define N_EDGES 320000
#define C_IN 128
#define C_OUT 128
#define KDIM 640            // 5 * 128

typedef __attribute__((ext_vector_type(8))) short short8;   // 8 bf16
typedef __attribute__((ext_vector_type(4))) float floatx4;  // MFMA C/D

// ---- bf16 helpers ---------------------------------------------------------
__device__ __forceinline__ unsigned short f2bf(float f) {
    unsigned int b = __float_as_uint(f);
    b = (b + 0x7FFFu + ((b >> 16) & 1u)) >> 16;   // RNE
    return (unsigned short)b;
}
__device__ __forceinline__ unsigned int pack2(float x, float y) {
    return (unsigned int)f2bf(x) | ((unsigned int)f2bf(y) << 16);
}

// ---------------------------------------------------------------------------
// SINGLE fused kernel. Block = 512 threads (8 waves) = 16 nodes. 625 blocks.
//
// Step 0: threads 0..16 binary-search sorted src for offsets[m0..m0+16]
//   (replaces the prep-offsets dispatch; ~19 L2-latency iterations, head
//   cost overlapped across blocks).
//
// Phase 1 (scatter): one node per wave, 2 nodes sequentially. e0/e1 forced
//   into SGPRs via readfirstlane -> dst[e], X[e][*] are wave-uniform s_loads
//   (SMEM pipe, zero VALU/vmem per-edge metadata). Lane l = channels
//   {2l,2l+1}, gathered DIRECTLY from f32 h as float2 (512 B/wave/edge,
//   coalesced; no bf16 pre-conversion dispatch, no hb4 HBM round-trip).
//   Unroll 8 -> 8 independent gathers in flight. f32 accumulate, pack bf16
//   into LDS Rs. Rs pitch 650 shorts = 325 dwords (ODD) -> A-frag
//   ds_read_b128 <=2-way banks (old 648 pitch gave stride%32=4 -> >=4-way).
//
// Phase 2 (GEMM): out(16x128) = Rs(16x640) x B(128x640)^T + bias.
//   B staged per 64-k chunk into LDS directly from f32 W with on-the-fly
//   transpose + f2bf (reads coalesced over o; kills the Wt prep). Bs pitch
//   66 shorts = 33 dwords (odd) -> staging writes & b128 reads <=2-way.
//   20x mfma_f32_16x16x32_bf16 per wave; D row=quad*4+r, col=lane&15
//   (verified rounds 3-9). Bias + nontemporal store epilogue.
// ---------------------------------------------------------------------------
__global__ __launch_bounds__(512, 4) void fused_spectconv(
        const float* __restrict__ h,           // (10000,128) f32
        const float* __restrict__ X,           // (320000,5)  f32
        const int* __restrict__ dst,
        const int* __restrict__ src,
        const float* __restrict__ W,           // (640,128)   f32
        const float* __restrict__ bias,
        float* __restrict__ out) {
    __shared__ int offs[17];
    __shared__ unsigned short Rs[16][650];     // 20.8 KB, odd dword pitch
    __shared__ unsigned short Bs[128][66];     // 16.9 KB, odd dword pitch

    const int tid = threadIdx.x;
    const int m0  = blockIdx.x * 16;           // 625 * 16 = 10000 exact

    // ---- Step 0: per-block CSR offsets ----
    if (tid < 17) {
        const int n = m0 + tid;
        int lo = 0, hi = N_EDGES;
        while (lo < hi) {
            const int mid = (lo + hi) >> 1;
            if (src[mid] < n) lo = mid + 1; else hi = mid;
        }
        offs[tid] = lo;
    }
    __syncthreads();

    const int wv   = __builtin_amdgcn_readfirstlane(tid >> 6);   // scalar 0..7
    const int lane = tid & 63;
    const float2* __restrict__ hf2 = (const float2*)h;   // row = 64 float2

    // ---- Phase 1: scatter ----
    for (int nn = 0; nn < 2; ++nn) {
        const int idx = wv * 2 + nn;
        const int e0 = __builtin_amdgcn_readfirstlane(offs[idx]);
        const int e1 = __builtin_amdgcn_readfirstlane(offs[idx + 1]);

        float a0x=0,a0y=0, a1x=0,a1y=0, a2x=0,a2y=0, a3x=0,a3y=0, a4x=0,a4y=0;

        int e = e0;
        for (; e + 7 < e1; e += 8) {           // scalar loop, unroll 8
            int d[8];
            float2 u[8];
#pragma unroll
            for (int q = 0; q < 8; ++q) d[q] = dst[e + q];        // s_loads
#pragma unroll
            for (int q = 0; q < 8; ++q)
                u[q] = hf2[(size_t)d[q] * 64 + lane];   // 8 gathers in flight
#pragma unroll
            for (int q = 0; q < 8; ++q) {
                const float* Xp = X + (size_t)(e + q) * 5;        // s_loads
                const float x0 = Xp[0], x1 = Xp[1], x2 = Xp[2], x3 = Xp[3], x4 = Xp[4];
                a0x = fmaf(x0, u[q].x, a0x); a0y = fmaf(x0, u[q].y, a0y);
                a1x = fmaf(x1, u[q].x, a1x); a1y = fmaf(x1, u[q].y, a1y);
                a2x = fmaf(x2, u[q].x, a2x); a2y = fmaf(x2, u[q].y, a2y);
                a3x = fmaf(x3, u[q].x, a3x); a3y = fmaf(x3, u[q].y, a3y);
                a4x = fmaf(x4, u[q].x, a4x); a4y = fmaf(x4, u[q].y, a4y);
            }
        }
        for (; e < e1; ++e) {                  // scalar tail
            const int d = dst[e];
            const float2 u = hf2[(size_t)d * 64 + lane];
            const float* Xp = X + (size_t)e * 5;
            const float x0 = Xp[0], x1 = Xp[1], x2 = Xp[2], x3 = Xp[3], x4 = Xp[4];
            a0x = fmaf(x0, u.x, a0x); a0y = fmaf(x0, u.y, a0y);
            a1x = fmaf(x1, u.x, a1x); a1y = fmaf(x1, u.y, a1y);
            a2x = fmaf(x2, u.x, a2x); a2y = fmaf(x2, u.y, a2y);
            a3x = fmaf(x3, u.x, a3x); a3y = fmaf(x3, u.y, a3y);
            a4x = fmaf(x4, u.x, a4x); a4y = fmaf(x4, u.y, a4y);
        }

        // Rs write: uint at [k*128 + 2*lane] -> dword addr idx*325+k*64+lane,
        // all 32 banks at 2-way (free).
        *(unsigned int*)&Rs[idx][0 * 128 + 2 * lane] = pack2(a0x, a0y);
        *(unsigned int*)&Rs[idx][1 * 128 + 2 * lane] = pack2(a1x, a1y);
        *(unsigned int*)&Rs[idx][2 * 128 + 2 * lane] = pack2(a2x, a2y);
        *(unsigned int*)&Rs[idx][3 * 128 + 2 * lane] = pack2(a3x, a3y);
        *(unsigned int*)&Rs[idx][4 * 128 + 2 * lane] = pack2(a4x, a4y);
    }

    __syncthreads();                           // Rs ready

    // ---- Phase 2: GEMM ----
    const int col  = lane & 15;
    const int quad = lane >> 4;
    const int c0   = wv * 16;

    floatx4 acc = {0.f, 0.f, 0.f, 0.f};

    for (int chunk = 0; chunk < 10; ++chunk) {
        if (chunk) __syncthreads();            // Bs consumed by prev chunk
        // Stage Bs[o][kk] = bf16(W[chunk*64+kk][o]), 64x128 elems.
        // 8 iters/thread: o = idx&127 (coalesced), kkpair = idx>>7 (0..31);
        // read 2 consecutive-k rows, pack, one b32 LDS write (2-way banks).
#pragma unroll
        for (int r = 0; r < 8; ++r) {
            const int i  = r * 512 + tid;
            const int o  = i & 127;
            const int kp = i >> 7;             // 0..31
            const float w0 = W[(size_t)(chunk * 64 + 2 * kp + 0) * C_OUT + o];
            const float w1 = W[(size_t)(chunk * 64 + 2 * kp + 1) * C_OUT + o];
            *(unsigned int*)&Bs[o][2 * kp] = pack2(w0, w1);
        }
        __syncthreads();                       // Bs ready

#pragma unroll
        for (int hh = 0; hh < 2; ++hh) {
            const short8 af = *(const short8*)&Rs[col][chunk * 64 + hh * 32 + quad * 8];
            const short8 bf = *(const short8*)&Bs[c0 + col][hh * 32 + quad * 8];
            acc = __builtin_amdgcn_mfma_f32_16x16x32_bf16(af, bf, acc, 0, 0, 0);
        }
    }

    const float bv = bias[c0 + col];
#pragma unroll
    for (int r = 0; r < 4; ++r) {
        const int m = m0 + quad * 4 + r;
        __builtin_nontemporal_store(acc[r] + bv, &out[(size_t)m * C_OUT + c0 + col]);
    }
}

// ---------------------------------------------------------------------------
extern "C" void kernel_launch(void* const* d_in, const int* in_sizes, int n_in,
                              void* d_out, int out_size, void* d_ws, size_t ws_size,
                              hipStream_t stream) {
    const float* h      = (const float*)d_in[0];   // (10000,128)
    const float* X      = (const float*)d_in[1];   // (320000,5)
    const int*   ei     = (const int*)d_in[2];     // (2,320000)
    const float* weight = (const float*)d_in[4];   // (5,128,128) == W(640,128)
    const float* bias   = (const float*)d_in[5];   // (128,)
    float* out = (float*)d_out;

    const int* src = ei;
    const int* dst = ei + N_EDGES;

    fused_spectconv<<<625, 512, 0, stream>>>(h, X, dst, src, weight, bias, out);
}